// Round 4
// baseline (76.265 us; speedup 1.0000x reference)
//
#include <hip/hip_runtime.h>

typedef __attribute__((ext_vector_type(4))) float f32x4;
typedef __attribute__((ext_vector_type(8))) short bf16x8;
typedef __attribute__((ext_vector_type(4))) unsigned short u16x4;

#define NB 8
#define LLEN 512
#define DD 768
#define MW 12
#define HH 384
#define TT (NB * LLEN)      // 4096 tokens
#define SS (LLEN * MW)      // 6144 spans per batch
#define KP (3 * HH)         // 1152 packed-K (hi/lo 3-pass)
#define MM (2 * TT)         // 8192 fused GEMM rows (U then V)

#define PACKH_BLOCKS ((TT * 192) / 256)   // 3072
#define PACKW_BLOCKS ((DD * 192) / 256)   // 576
#define SENT_BLOCKS (DD / 4)              // 192
#define PREP_BLOCKS (PACKH_BLOCKS + PACKW_BLOCKS + SENT_BLOCKS)

// ---------- helpers ----------
__device__ __forceinline__ unsigned short f2bf(float x) {
  unsigned u = __builtin_bit_cast(unsigned, x);
  u += 0x7fff + ((u >> 16) & 1);              // RNE
  return (unsigned short)(u >> 16);
}
__device__ __forceinline__ float bf2f(unsigned short b) {
  return __builtin_bit_cast(float, (unsigned)b << 16);
}
__device__ __forceinline__ void gload_lds16(const void* g, void* l) {
  __builtin_amdgcn_global_load_lds(
      (const __attribute__((address_space(1))) unsigned int*)g,
      (__attribute__((address_space(3))) unsigned int*)l, 16, 0, 0);
}

// ---------- prep: h -> A ([hi|hi|lo], fwd rows 0..TT-1, bwd rows TT..2TT-1),
//                  W -> Bu,Bv ([hi|lo|hi]), sentinels -> us,vs (bf16) ----------
__global__ __launch_bounds__(256) void prep_k(const float* __restrict__ h,
                                              const float* __restrict__ W,
                                              const float* __restrict__ ss,
                                              const float* __restrict__ es,
                                              unsigned short* __restrict__ A,
                                              unsigned short* __restrict__ Bu,
                                              unsigned short* __restrict__ Bv,
                                              unsigned short* __restrict__ us,
                                              unsigned short* __restrict__ vs) {
  int bid = blockIdx.x;
  if (bid < PACKH_BLOCKS) {
    int idx = bid * 256 + threadIdx.x;        // over TT*192 float4s
    int t = idx / 192;
    int k = (idx - t * 192) * 4;
    f32x4 f = *(const f32x4*)(h + (size_t)idx * 4);
    int row = (k < HH) ? t : TT + t;          // fwd half -> U rows, bwd -> V rows
    int kk = (k < HH) ? k : k - HH;
    u16x4 hi, lo;
#pragma unroll
    for (int j = 0; j < 4; ++j) {
      float x = f[j];
      unsigned short hb = f2bf(x);
      hi[j] = hb;
      lo[j] = f2bf(x - bf2f(hb));
    }
    unsigned short* base = A + (size_t)row * KP + kk;
    *(u16x4*)(base) = hi;
    *(u16x4*)(base + HH) = hi;
    *(u16x4*)(base + 2 * HH) = lo;
  } else if (bid < PACKH_BLOCKS + PACKW_BLOCKS) {
    int idx = (bid - PACKH_BLOCKS) * 256 + threadIdx.x;  // over DD*192 float4s
    int e = idx / 192;
    int k = (idx - e * 192) * 4;
    f32x4 f = *(const f32x4*)(W + (size_t)idx * 4);
    unsigned short* Bm = (k < HH) ? Bu : Bv;
    int kk = (k < HH) ? k : k - HH;
    u16x4 hi, lo;
#pragma unroll
    for (int j = 0; j < 4; ++j) {
      float x = f[j];
      unsigned short hb = f2bf(x);
      hi[j] = hb;
      lo[j] = f2bf(x - bf2f(hb));
    }
    unsigned short* base = Bm + (size_t)e * KP + kk;
    *(u16x4*)(base) = hi;
    *(u16x4*)(base + HH) = lo;
    *(u16x4*)(base + 2 * HH) = hi;
  } else {
    // sentinel projections: 4 e-values per block, 64 lanes each
    int e = (bid - PACKH_BLOCKS - PACKW_BLOCKS) * 4 + (threadIdx.x >> 6);
    int lane = threadIdx.x & 63;
    float a = 0.f, b = 0.f;
    const float* w = W + (size_t)e * DD;
    for (int j = lane; j < HH; j += 64) {
      a += ss[j] * w[j];
      b += es[j] * w[HH + j];
    }
#pragma unroll
    for (int off = 32; off > 0; off >>= 1) {
      a += __shfl_down(a, off);
      b += __shfl_down(b, off);
    }
    if (lane == 0) { us[e] = f2bf(a); vs[e] = f2bf(b); }
  }
}

// ---------- fused bf16 GEMM: C[M=8192][N=768] = A[M][KP] * B^T[N][KP], C in bf16 ----------
// BM=128, BN=96, BK=128 -> grid 64x8 = 512 blocks = 2/CU; 9 K-iters (half the barriers of BK=64).
__global__ __launch_bounds__(256) void gemm_k(const unsigned short* __restrict__ A,
                                              const unsigned short* __restrict__ Bu,
                                              const unsigned short* __restrict__ Bv,
                                              unsigned short* __restrict__ C) {
  __shared__ unsigned short As[128 * 128];  // 32 KB
  __shared__ unsigned short Bs[96 * 128];   // 24 KB

  const int tid = threadIdx.x;
  const int lane = tid & 63;
  const int w = tid >> 6;
  const int wr = w >> 1, wc = w & 1;        // 2x2 waves -> each 64x48
  const int l16 = lane & 15, l4 = lane >> 4;
  const int row0 = blockIdx.x * 128;
  const int col0 = blockIdx.y * 96;
  const unsigned short* Bm = (row0 < TT) ? Bu : Bv;

  f32x4 acc[4][3] = {};
  const char* Ab = (const char*)A;
  const char* Bb = (const char*)Bm;

  for (int k0 = 0; k0 < KP; k0 += 128) {
    // stage A 128x128 (32KB: 8 16B-loads/thread), B^T 96x128 (24KB: 6 loads/thread)
#pragma unroll
    for (int r = 0; r < 8; ++r) {
      int o = (r * 256 + tid) * 16;         // byte offset; 256 B per LDS row
      int row = o >> 8, colb = o & 255;
      gload_lds16(Ab + ((size_t)(row0 + row) * KP + k0) * 2 + colb, (char*)As + o);
    }
#pragma unroll
    for (int r = 0; r < 6; ++r) {
      int o = (r * 256 + tid) * 16;
      int row = o >> 8, colb = o & 255;
      gload_lds16(Bb + ((size_t)(col0 + row) * KP + k0) * 2 + colb, (char*)Bs + o);
    }
    __syncthreads();

#pragma unroll
    for (int ks = 0; ks < 4; ++ks) {        // 4 x K=32 sub-steps
      bf16x8 af[4], bfr[3];
#pragma unroll
      for (int m = 0; m < 4; ++m)
        af[m] = *(const bf16x8*)&As[(wr * 64 + m * 16 + l16) * 128 + ks * 32 + l4 * 8];
#pragma unroll
      for (int n = 0; n < 3; ++n)
        bfr[n] = *(const bf16x8*)&Bs[(wc * 48 + n * 16 + l16) * 128 + ks * 32 + l4 * 8];
#pragma unroll
      for (int m = 0; m < 4; ++m)
#pragma unroll
        for (int n = 0; n < 3; ++n)
          acc[m][n] = __builtin_amdgcn_mfma_f32_16x16x32_bf16(af[m], bfr[n], acc[m][n], 0, 0, 0);
    }
    __syncthreads();
  }

  // epilogue: D row=(lane>>4)*4+reg, col=lane&15 (m89-verified); store bf16
#pragma unroll
  for (int m = 0; m < 4; ++m) {
    int grow = row0 + wr * 64 + m * 16 + l4 * 4;
#pragma unroll
    for (int n = 0; n < 3; ++n) {
      int gcol = col0 + wc * 48 + n * 16 + l16;
#pragma unroll
      for (int r = 0; r < 4; ++r)
        C[(size_t)(grow + r) * DD + gcol] = f2bf(acc[m][n][r]);
    }
  }
}

// ---------- assembly: one block per token (XCD-swizzled), loops its 12 spans ----------
__global__ __launch_bounds__(192) void assemble_k(const int* __restrict__ span,
                                                  const unsigned short* __restrict__ U,
                                                  const unsigned short* __restrict__ V,
                                                  const unsigned short* __restrict__ us,
                                                  const unsigned short* __restrict__ vs,
                                                  const float* __restrict__ bias,
                                                  float* __restrict__ out) {
  const int bid = blockIdx.x;
  const int tk = (bid & 7) * (TT / 8) + (bid >> 3);   // XCD-chunked token order
  const int b = tk >> 9;                     // /512
  const int l = tk & 511;
  const int t0 = b * LLEN;
  const int e4 = threadIdx.x;                // 0..191, covers 4 e's
  const u16x4* U4 = (const u16x4*)U;
  const u16x4* V4 = (const u16x4*)V;
  const f32x4 bb = ((const f32x4*)bias)[e4];
  const size_t sbase = ((size_t)b * SS + (size_t)l * MW) * 2;
  f32x4* out4 = (f32x4*)out + ((size_t)b * SS + (size_t)l * MW) * 192 + e4;

#pragma unroll 4
  for (int wdx = 0; wdx < MW; ++wdx) {
    const int start = span[sbase + 2 * wdx];
    const int end   = span[sbase + 2 * wdx + 1];
    u16x4 pe = U4[(size_t)(t0 + end) * 192 + e4];
    u16x4 pv = (end + 1 >= LLEN) ? ((const u16x4*)vs)[e4]
                                 : V4[(size_t)(t0 + end + 1) * 192 + e4];
    u16x4 mu = (start == 0) ? ((const u16x4*)us)[e4]
                            : U4[(size_t)(t0 + start - 1) * 192 + e4];
    u16x4 mv = V4[(size_t)(t0 + start) * 192 + e4];
    f32x4 r;
#pragma unroll
    for (int j = 0; j < 4; ++j) {
      float x = bf2f(pe[j]) + bf2f(pv[j]) - bf2f(mu[j]) - bf2f(mv[j]) + bb[j];
      r[j] = fmaxf(x, 0.f);
    }
    out4[(size_t)wdx * 192] = r;
  }
}

// ---------- naive fallback (only if ws too small) ----------
__global__ __launch_bounds__(256) void naive_k(const float* __restrict__ h,
                                               const int* __restrict__ span,
                                               const float* __restrict__ W,
                                               const float* __restrict__ bias,
                                               const float* __restrict__ ss,
                                               const float* __restrict__ es,
                                               float* __restrict__ out) {
  int bs = blockIdx.x;
  int b = bs / SS;
  int start = span[(size_t)bs * 2 + 0];
  int end   = span[(size_t)bs * 2 + 1];
  __shared__ float rep[DD];
  const float* hb = h + (size_t)b * LLEN * DD;
  for (int k = threadIdx.x; k < HH; k += blockDim.x) {
    float fs = (start == 0) ? ss[k] : hb[(size_t)(start - 1) * DD + k];
    rep[k] = hb[(size_t)end * DD + k] - fs;
    float bstart = (end + 1 >= LLEN) ? es[k] : hb[(size_t)(end + 1) * DD + HH + k];
    rep[HH + k] = bstart - hb[(size_t)start * DD + HH + k];
  }
  __syncthreads();
  for (int e = threadIdx.x; e < DD; e += blockDim.x) {
    const float* w = W + (size_t)e * DD;
    float acc = bias[e];
    for (int k = 0; k < DD; k += 4) {
      acc += rep[k] * w[k] + rep[k + 1] * w[k + 1] + rep[k + 2] * w[k + 2] + rep[k + 3] * w[k + 3];
    }
    out[(size_t)bs * DD + e] = fmaxf(acc, 0.f);
  }
}

extern "C" void kernel_launch(void* const* d_in, const int* in_sizes, int n_in,
                              void* d_out, int out_size, void* d_ws, size_t ws_size,
                              hipStream_t stream) {
  const float* h  = (const float*)d_in[0];
  const int* span = (const int*)d_in[1];
  const float* W  = (const float*)d_in[2];
  const float* bias = (const float*)d_in[3];
  const float* ss = (const float*)d_in[4];
  const float* es = (const float*)d_in[5];
  float* out = (float*)d_out;

  const size_t szUV = (size_t)MM * DD * sizeof(unsigned short);   // 12.58 MB (U+V bf16)
  const size_t szA  = (size_t)MM * KP * sizeof(unsigned short);   // 18.87 MB
  const size_t szB  = (size_t)DD * KP * sizeof(unsigned short);   // 1.77 MB
  const size_t szS  = DD * sizeof(unsigned short);
  const size_t need = szUV + szA + 2 * szB + 2 * szS;             // ~35 MB

  if (ws_size < need) {
    naive_k<<<NB * SS, 256, 0, stream>>>(h, span, W, bias, ss, es, out);
    return;
  }

  char* ws = (char*)d_ws;
  unsigned short* U = (unsigned short*)ws;                 // [TT][DD] bf16
  unsigned short* V = U + (size_t)TT * DD;                 // [TT][DD] bf16 (GEMM rows TT..)
  unsigned short* A  = (unsigned short*)(ws + szUV);       // [MM][KP]
  unsigned short* Bu = (unsigned short*)(ws + szUV + szA);
  unsigned short* Bv = (unsigned short*)(ws + szUV + szA + szB);
  unsigned short* us = (unsigned short*)(ws + szUV + szA + 2 * szB);
  unsigned short* vs = us + DD;

  prep_k<<<PREP_BLOCKS, 256, 0, stream>>>(h, W, ss, es, A, Bu, Bv, us, vs);
  gemm_k<<<dim3(MM / 128, DD / 96), 256, 0, stream>>>(A, Bu, Bv, U);
  assemble_k<<<TT, 192, 0, stream>>>(span, U, V, us, vs, bias, out);
}

// Round 5
// 66.996 us; speedup vs baseline: 1.1384x; 1.1384x over previous
//
#include <hip/hip_runtime.h>

typedef __attribute__((ext_vector_type(4))) float f32x4;
typedef __attribute__((ext_vector_type(8))) short bf16x8;
typedef __attribute__((ext_vector_type(4))) unsigned short u16x4;

#define NB 8
#define LLEN 512
#define DD 768
#define MW 12
#define HH 384
#define TT (NB * LLEN)      // 4096 tokens
#define SS (LLEN * MW)      // 6144 spans per batch
#define KP (3 * HH)         // 1152 effective K (3-pass hi/lo)
#define MM (2 * TT)         // 8192 fused GEMM rows (U rows then V rows)

#define PACKH_BLOCKS ((TT * 192) / 256)   // 3072
#define PACKW_BLOCKS ((DD * 192) / 256)   // 576
#define SENT_BLOCKS (DD / 4)              // 192
#define PREP_BLOCKS (PACKH_BLOCKS + PACKW_BLOCKS + SENT_BLOCKS)

// ---------- helpers ----------
__device__ __forceinline__ unsigned short f2bf(float x) {
  unsigned u = __builtin_bit_cast(unsigned, x);
  u += 0x7fff + ((u >> 16) & 1);              // RNE
  return (unsigned short)(u >> 16);
}
__device__ __forceinline__ float bf2f(unsigned short b) {
  return __builtin_bit_cast(float, (unsigned)b << 16);
}
__device__ __forceinline__ void gload_lds16(const void* g, void* l) {
  __builtin_amdgcn_global_load_lds(
      (const __attribute__((address_space(1))) unsigned int*)g,
      (__attribute__((address_space(3))) unsigned int*)l, 16, 0, 0);
}

// ---------- prep: h -> Ahi/Alo [MM][HH] (fwd rows 0..TT-1, bwd rows TT..),
//                  W -> Bu{hi,lo}, Bv{hi,lo} [DD][HH]; sentinels -> us,vs bf16 ----------
__global__ __launch_bounds__(256) void prep_k(const float* __restrict__ h,
                                              const float* __restrict__ W,
                                              const float* __restrict__ ss,
                                              const float* __restrict__ es,
                                              unsigned short* __restrict__ Ahi,
                                              unsigned short* __restrict__ Alo,
                                              unsigned short* __restrict__ Buhi,
                                              unsigned short* __restrict__ Bulo,
                                              unsigned short* __restrict__ Bvhi,
                                              unsigned short* __restrict__ Bvlo,
                                              unsigned short* __restrict__ us,
                                              unsigned short* __restrict__ vs) {
  int bid = blockIdx.x;
  if (bid < PACKH_BLOCKS) {
    int idx = bid * 256 + threadIdx.x;        // over TT*192 float4s
    int t = idx / 192;
    int k = (idx - t * 192) * 4;
    f32x4 f = *(const f32x4*)(h + (size_t)idx * 4);
    int row = (k < HH) ? t : TT + t;          // fwd half -> U rows, bwd -> V rows
    int kk = (k < HH) ? k : k - HH;
    u16x4 hi, lo;
#pragma unroll
    for (int j = 0; j < 4; ++j) {
      float x = f[j];
      unsigned short hb = f2bf(x);
      hi[j] = hb;
      lo[j] = f2bf(x - bf2f(hb));
    }
    *(u16x4*)(Ahi + (size_t)row * HH + kk) = hi;
    *(u16x4*)(Alo + (size_t)row * HH + kk) = lo;
  } else if (bid < PACKH_BLOCKS + PACKW_BLOCKS) {
    int idx = (bid - PACKH_BLOCKS) * 256 + threadIdx.x;  // over DD*192 float4s
    int e = idx / 192;
    int k = (idx - e * 192) * 4;
    f32x4 f = *(const f32x4*)(W + (size_t)idx * 4);
    unsigned short* Bh = (k < HH) ? Buhi : Bvhi;
    unsigned short* Bl = (k < HH) ? Bulo : Bvlo;
    int kk = (k < HH) ? k : k - HH;
    u16x4 hi, lo;
#pragma unroll
    for (int j = 0; j < 4; ++j) {
      float x = f[j];
      unsigned short hb = f2bf(x);
      hi[j] = hb;
      lo[j] = f2bf(x - bf2f(hb));
    }
    *(u16x4*)(Bh + (size_t)e * HH + kk) = hi;
    *(u16x4*)(Bl + (size_t)e * HH + kk) = lo;
  } else {
    // sentinel projections: 4 e-values per block, 64 lanes each
    int e = (bid - PACKH_BLOCKS - PACKW_BLOCKS) * 4 + (threadIdx.x >> 6);
    int lane = threadIdx.x & 63;
    float a = 0.f, b = 0.f;
    const float* w = W + (size_t)e * DD;
    for (int j = lane; j < HH; j += 64) {
      a += ss[j] * w[j];
      b += es[j] * w[HH + j];
    }
#pragma unroll
    for (int off = 32; off > 0; off >>= 1) {
      a += __shfl_down(a, off);
      b += __shfl_down(b, off);
    }
    if (lane == 0) { us[e] = f2bf(a); vs[e] = f2bf(b); }
  }
}

// ---------- fused 3-pass bf16 GEMM: C[8192][768] = A*B^T, C bf16 ----------
// BM=128, BN=96, BK=64, 18 K-iters: seg0=Ahi*Bhi, seg1=Ahi*Blo, seg2=Alo*Bhi.
// 1-D grid 512, x=bid&63 -> bid%8==x%8: all 8 N-blocks of an M-panel share an XCD (L2-resident A).
__global__ __launch_bounds__(256) void gemm_k(const unsigned short* __restrict__ Ahi,
                                              const unsigned short* __restrict__ Alo,
                                              const unsigned short* __restrict__ Buhi,
                                              const unsigned short* __restrict__ Bulo,
                                              const unsigned short* __restrict__ Bvhi,
                                              const unsigned short* __restrict__ Bvlo,
                                              unsigned short* __restrict__ C) {
  __shared__ unsigned short As[128 * 64];   // 16 KB
  __shared__ unsigned short Bs[96 * 64];    // 12 KB

  const int bid = blockIdx.x;
  const int bx = bid & 63, by = bid >> 6;
  const int tid = threadIdx.x;
  const int lane = tid & 63;
  const int w = tid >> 6;
  const int wr = w >> 1, wc = w & 1;        // 2x2 waves -> each 64x48
  const int l16 = lane & 15, l4 = lane >> 4;
  const int row0 = bx * 128;
  const int col0 = by * 96;
  const unsigned short* Bhi = (row0 < TT) ? Buhi : Bvhi;
  const unsigned short* Blo = (row0 < TT) ? Bulo : Bvlo;

  f32x4 acc[4][3] = {};

  for (int k0 = 0; k0 < KP; k0 += 64) {
    const int seg = k0 / HH;                      // 0,1,2
    const int kc = k0 - seg * HH;                 // column within [0,384)
    const char* Ab = (const char*)((seg < 2) ? Ahi : Alo);
    const char* Bb = (const char*)((seg == 1) ? Blo : Bhi);
    // stage A 128x64 (16KB: 4 16B-loads/thread), B^T 96x64 (12KB: 3 loads/thread)
#pragma unroll
    for (int r = 0; r < 4; ++r) {
      int o = (r * 256 + tid) * 16;         // byte offset; 128 B per LDS row
      int row = o >> 7, colb = o & 127;
      gload_lds16(Ab + ((size_t)(row0 + row) * HH + kc) * 2 + colb, (char*)As + o);
    }
#pragma unroll
    for (int r = 0; r < 3; ++r) {
      int o = (r * 256 + tid) * 16;
      int row = o >> 7, colb = o & 127;
      gload_lds16(Bb + ((size_t)(col0 + row) * HH + kc) * 2 + colb, (char*)Bs + o);
    }
    __syncthreads();

    bf16x8 af[2][4], bfr[2][3];
#pragma unroll
    for (int ks = 0; ks < 2; ++ks)
#pragma unroll
      for (int m = 0; m < 4; ++m)
        af[ks][m] = *(const bf16x8*)&As[(wr * 64 + m * 16 + l16) * 64 + ks * 32 + l4 * 8];
#pragma unroll
    for (int ks = 0; ks < 2; ++ks)
#pragma unroll
      for (int n = 0; n < 3; ++n)
        bfr[ks][n] = *(const bf16x8*)&Bs[(wc * 48 + n * 16 + l16) * 64 + ks * 32 + l4 * 8];

#pragma unroll
    for (int m = 0; m < 4; ++m)
#pragma unroll
      for (int n = 0; n < 3; ++n) {
        acc[m][n] = __builtin_amdgcn_mfma_f32_16x16x32_bf16(af[0][m], bfr[0][n], acc[m][n], 0, 0, 0);
        acc[m][n] = __builtin_amdgcn_mfma_f32_16x16x32_bf16(af[1][m], bfr[1][n], acc[m][n], 0, 0, 0);
      }
    __syncthreads();
  }

  // epilogue: D row=(lane>>4)*4+reg, col=lane&15 (m89-verified); store bf16
#pragma unroll
  for (int m = 0; m < 4; ++m) {
    int grow = row0 + wr * 64 + m * 16 + l4 * 4;
#pragma unroll
    for (int n = 0; n < 3; ++n) {
      int gcol = col0 + wc * 48 + n * 16 + l16;
#pragma unroll
      for (int r = 0; r < 4; ++r)
        C[(size_t)(grow + r) * DD + gcol] = f2bf(acc[m][n][r]);
    }
  }
}

// ---------- assembly: one block per token (XCD-swizzled), loops its 12 spans ----------
__global__ __launch_bounds__(192) void assemble_k(const int* __restrict__ span,
                                                  const unsigned short* __restrict__ U,
                                                  const unsigned short* __restrict__ V,
                                                  const unsigned short* __restrict__ us,
                                                  const unsigned short* __restrict__ vs,
                                                  const float* __restrict__ bias,
                                                  float* __restrict__ out) {
  const int bid = blockIdx.x;
  const int tk = (bid & 7) * (TT / 8) + (bid >> 3);   // XCD-chunked token order
  const int b = tk >> 9;                     // /512
  const int l = tk & 511;
  const int t0 = b * LLEN;
  const int e4 = threadIdx.x;                // 0..191, covers 4 e's
  const u16x4* U4 = (const u16x4*)U;
  const u16x4* V4 = (const u16x4*)V;
  const f32x4 bb = ((const f32x4*)bias)[e4];
  const int2* sp = (const int2*)(span + ((size_t)b * SS + (size_t)l * MW) * 2);
  f32x4* out4 = (f32x4*)out + ((size_t)b * SS + (size_t)l * MW) * 192 + e4;

#pragma unroll 4
  for (int wdx = 0; wdx < MW; ++wdx) {
    const int2 se = sp[wdx];
    const int start = se.x, end = se.y;
    u16x4 pe = U4[(size_t)(t0 + end) * 192 + e4];
    u16x4 pv = (end + 1 >= LLEN) ? ((const u16x4*)vs)[e4]
                                 : V4[(size_t)(t0 + end + 1) * 192 + e4];
    u16x4 mu = (start == 0) ? ((const u16x4*)us)[e4]
                            : U4[(size_t)(t0 + start - 1) * 192 + e4];
    u16x4 mv = V4[(size_t)(t0 + start) * 192 + e4];
    f32x4 r;
#pragma unroll
    for (int j = 0; j < 4; ++j) {
      float x = bf2f(pe[j]) + bf2f(pv[j]) - bf2f(mu[j]) - bf2f(mv[j]) + bb[j];
      r[j] = fmaxf(x, 0.f);
    }
    out4[(size_t)wdx * 192] = r;
  }
}

// ---------- naive fallback (only if ws too small) ----------
__global__ __launch_bounds__(256) void naive_k(const float* __restrict__ h,
                                               const int* __restrict__ span,
                                               const float* __restrict__ W,
                                               const float* __restrict__ bias,
                                               const float* __restrict__ ss,
                                               const float* __restrict__ es,
                                               float* __restrict__ out) {
  int bs = blockIdx.x;
  int b = bs / SS;
  int start = span[(size_t)bs * 2 + 0];
  int end   = span[(size_t)bs * 2 + 1];
  __shared__ float rep[DD];
  const float* hb = h + (size_t)b * LLEN * DD;
  for (int k = threadIdx.x; k < HH; k += blockDim.x) {
    float fs = (start == 0) ? ss[k] : hb[(size_t)(start - 1) * DD + k];
    rep[k] = hb[(size_t)end * DD + k] - fs;
    float bstart = (end + 1 >= LLEN) ? es[k] : hb[(size_t)(end + 1) * DD + HH + k];
    rep[HH + k] = bstart - hb[(size_t)start * DD + HH + k];
  }
  __syncthreads();
  for (int e = threadIdx.x; e < DD; e += blockDim.x) {
    const float* w = W + (size_t)e * DD;
    float acc = bias[e];
    for (int k = 0; k < DD; k += 4) {
      acc += rep[k] * w[k] + rep[k + 1] * w[k + 1] + rep[k + 2] * w[k + 2] + rep[k + 3] * w[k + 3];
    }
    out[(size_t)bs * DD + e] = fmaxf(acc, 0.f);
  }
}

extern "C" void kernel_launch(void* const* d_in, const int* in_sizes, int n_in,
                              void* d_out, int out_size, void* d_ws, size_t ws_size,
                              hipStream_t stream) {
  const float* h  = (const float*)d_in[0];
  const int* span = (const int*)d_in[1];
  const float* W  = (const float*)d_in[2];
  const float* bias = (const float*)d_in[3];
  const float* ss = (const float*)d_in[4];
  const float* es = (const float*)d_in[5];
  float* out = (float*)d_out;

  const size_t szUV = (size_t)MM * DD * sizeof(unsigned short);   // 12.58 MB (U+V bf16)
  const size_t szA  = (size_t)MM * HH * sizeof(unsigned short);   // 6.29 MB (each of hi/lo)
  const size_t szB  = (size_t)DD * HH * sizeof(unsigned short);   // 0.59 MB (each)
  const size_t szS  = DD * sizeof(unsigned short);
  const size_t need = szUV + 2 * szA + 4 * szB + 2 * szS;         // ~27.6 MB

  if (ws_size < need) {
    naive_k<<<NB * SS, 256, 0, stream>>>(h, span, W, bias, ss, es, out);
    return;
  }

  char* ws = (char*)d_ws;
  unsigned short* U    = (unsigned short*)ws;              // [TT][DD] bf16
  unsigned short* V    = U + (size_t)TT * DD;              // [TT][DD] bf16
  unsigned short* Ahi  = (unsigned short*)(ws + szUV);
  unsigned short* Alo  = Ahi + (size_t)MM * HH;
  unsigned short* Buhi = Alo + (size_t)MM * HH;
  unsigned short* Bulo = Buhi + (size_t)DD * HH;
  unsigned short* Bvhi = Bulo + (size_t)DD * HH;
  unsigned short* Bvlo = Bvhi + (size_t)DD * HH;
  unsigned short* us   = Bvlo + (size_t)DD * HH;
  unsigned short* vs   = us + DD;

  prep_k<<<PREP_BLOCKS, 256, 0, stream>>>(h, W, ss, es, Ahi, Alo, Buhi, Bulo, Bvhi, Bvlo, us, vs);
  gemm_k<<<512, 256, 0, stream>>>(Ahi, Alo, Buhi, Bulo, Bvhi, Bvlo, U);
  assemble_k<<<TT, 192, 0, stream>>>(span, U, V, us, vs, bias, out);
}

// Round 7
// 53.330 us; speedup vs baseline: 1.4301x; 1.2563x over previous
//
#include <hip/hip_runtime.h>

typedef __attribute__((ext_vector_type(4))) float f32x4;
typedef __attribute__((ext_vector_type(8))) short bf16x8;
typedef __attribute__((ext_vector_type(4))) unsigned short u16x4;

#define NB 8
#define LLEN 512
#define DD 768
#define MW 12
#define HH 384
#define TT (NB * LLEN)      // 4096 tokens
#define SS (LLEN * MW)      // 6144 spans per batch
#define MM (2 * TT)         // 8192 fused GEMM rows (U rows then V rows)

#define PACKH_BLOCKS ((TT * 192) / 256)   // 3072
#define PACKW_BLOCKS ((DD * 192) / 256)   // 576
#define SENT_BLOCKS (DD / 4)              // 192
#define PREP_BLOCKS (PACKH_BLOCKS + PACKW_BLOCKS + SENT_BLOCKS)

// ---------- helpers ----------
__device__ __forceinline__ unsigned short f2bf(float x) {
  unsigned u = __builtin_bit_cast(unsigned, x);
  u += 0x7fff + ((u >> 16) & 1);              // RNE
  return (unsigned short)(u >> 16);
}
__device__ __forceinline__ float bf2f(unsigned short b) {
  return __builtin_bit_cast(float, (unsigned)b << 16);
}
__device__ __forceinline__ unsigned short f2h(float x) {
  _Float16 h = (_Float16)x;
  return __builtin_bit_cast(unsigned short, h);
}
__device__ __forceinline__ float h2f(unsigned short u) {
  return (float)__builtin_bit_cast(_Float16, u);
}
__device__ __forceinline__ void gload_lds16(const void* g, void* l) {
  __builtin_amdgcn_global_load_lds(
      (const __attribute__((address_space(1))) unsigned int*)g,
      (__attribute__((address_space(3))) unsigned int*)l, 16, 0, 0);
}

// ---------- prep: h -> Ahi [MM][HH] bf16 (fwd rows 0..TT-1, bwd rows TT..),
//                  W -> Bu{hi,lo}, Bv{hi,lo} [DD][HH] bf16; sentinels -> us,vs fp16 ----------
__global__ __launch_bounds__(256) void prep_k(const float* __restrict__ h,
                                              const float* __restrict__ W,
                                              const float* __restrict__ ss,
                                              const float* __restrict__ es,
                                              unsigned short* __restrict__ Ahi,
                                              unsigned short* __restrict__ Buhi,
                                              unsigned short* __restrict__ Bulo,
                                              unsigned short* __restrict__ Bvhi,
                                              unsigned short* __restrict__ Bvlo,
                                              unsigned short* __restrict__ us,
                                              unsigned short* __restrict__ vs) {
  int bid = blockIdx.x;
  if (bid < PACKH_BLOCKS) {
    int idx = bid * 256 + threadIdx.x;        // over TT*192 float4s
    int t = idx / 192;
    int k = (idx - t * 192) * 4;
    f32x4 f = *(const f32x4*)(h + (size_t)idx * 4);
    int row = (k < HH) ? t : TT + t;          // fwd half -> U rows, bwd -> V rows
    int kk = (k < HH) ? k : k - HH;
    u16x4 hi;
#pragma unroll
    for (int j = 0; j < 4; ++j) hi[j] = f2bf(f[j]);
    *(u16x4*)(Ahi + (size_t)row * HH + kk) = hi;
  } else if (bid < PACKH_BLOCKS + PACKW_BLOCKS) {
    int idx = (bid - PACKH_BLOCKS) * 256 + threadIdx.x;  // over DD*192 float4s
    int e = idx / 192;
    int k = (idx - e * 192) * 4;
    f32x4 f = *(const f32x4*)(W + (size_t)idx * 4);
    unsigned short* Bh = (k < HH) ? Buhi : Bvhi;
    unsigned short* Bl = (k < HH) ? Bulo : Bvlo;
    int kk = (k < HH) ? k : k - HH;
    u16x4 hi, lo;
#pragma unroll
    for (int j = 0; j < 4; ++j) {
      float x = f[j];
      unsigned short hb = f2bf(x);
      hi[j] = hb;
      lo[j] = f2bf(x - bf2f(hb));
    }
    *(u16x4*)(Bh + (size_t)e * HH + kk) = hi;
    *(u16x4*)(Bl + (size_t)e * HH + kk) = lo;
  } else {
    // sentinel projections: 4 e-values per block, 64 lanes each
    int e = (bid - PACKH_BLOCKS - PACKW_BLOCKS) * 4 + (threadIdx.x >> 6);
    int lane = threadIdx.x & 63;
    float a = 0.f, b = 0.f;
    const float* w = W + (size_t)e * DD;
    for (int j = lane; j < HH; j += 64) {
      a += ss[j] * w[j];
      b += es[j] * w[HH + j];
    }
#pragma unroll
    for (int off = 32; off > 0; off >>= 1) {
      a += __shfl_down(a, off);
      b += __shfl_down(b, off);
    }
    if (lane == 0) { us[e] = f2h(a); vs[e] = f2h(b); }
  }
}

// ---------- fused GEMM: C[8192][768] = bf16(A) * (Bhi+Blo)^T, C fp16 ----------
// BM=128, BN=96, kc-loop 6 iters; per iter stage A + Bhi + Blo (40 KB LDS),
// both B-passes accumulate into the same acc. Grid 512 = 2/CU; bid&63 keeps
// an M-panel's 8 N-blocks on one XCD (L2-resident A).
__global__ __launch_bounds__(256) void gemm_k(const unsigned short* __restrict__ Ahi,
                                              const unsigned short* __restrict__ Buhi,
                                              const unsigned short* __restrict__ Bulo,
                                              const unsigned short* __restrict__ Bvhi,
                                              const unsigned short* __restrict__ Bvlo,
                                              unsigned short* __restrict__ C) {
  __shared__ unsigned short As[128 * 64];    // 16 KB
  __shared__ unsigned short Bsh[96 * 64];    // 12 KB
  __shared__ unsigned short Bsl[96 * 64];    // 12 KB

  const int bid = blockIdx.x;
  const int bx = bid & 63, by = bid >> 6;
  const int tid = threadIdx.x;
  const int lane = tid & 63;
  const int w = tid >> 6;
  const int wr = w >> 1, wc = w & 1;         // 2x2 waves -> each 64x48
  const int l16 = lane & 15, l4 = lane >> 4;
  const int row0 = bx * 128;
  const int col0 = by * 96;
  const char* Bhi = (const char*)((row0 < TT) ? Buhi : Bvhi);
  const char* Blo = (const char*)((row0 < TT) ? Bulo : Bvlo);
  const char* Ab = (const char*)Ahi;

  f32x4 acc[4][3] = {};

  for (int kc = 0; kc < HH; kc += 64) {
    // stage A 128x64 (4 loads/thread), Bhi 96x64 (3), Blo 96x64 (3)
#pragma unroll
    for (int r = 0; r < 4; ++r) {
      int o = (r * 256 + tid) * 16;          // byte offset; 128 B per LDS row
      int row = o >> 7, colb = o & 127;
      gload_lds16(Ab + ((size_t)(row0 + row) * HH + kc) * 2 + colb, (char*)As + o);
    }
#pragma unroll
    for (int r = 0; r < 3; ++r) {
      int o = (r * 256 + tid) * 16;
      int row = o >> 7, colb = o & 127;
      gload_lds16(Bhi + ((size_t)(col0 + row) * HH + kc) * 2 + colb, (char*)Bsh + o);
      gload_lds16(Blo + ((size_t)(col0 + row) * HH + kc) * 2 + colb, (char*)Bsl + o);
    }
    __syncthreads();

    bf16x8 af[2][4], bh[2][3], bl[2][3];
#pragma unroll
    for (int ks = 0; ks < 2; ++ks)
#pragma unroll
      for (int m = 0; m < 4; ++m)
        af[ks][m] = *(const bf16x8*)&As[(wr * 64 + m * 16 + l16) * 64 + ks * 32 + l4 * 8];
#pragma unroll
    for (int ks = 0; ks < 2; ++ks)
#pragma unroll
      for (int n = 0; n < 3; ++n) {
        bh[ks][n] = *(const bf16x8*)&Bsh[(wc * 48 + n * 16 + l16) * 64 + ks * 32 + l4 * 8];
        bl[ks][n] = *(const bf16x8*)&Bsl[(wc * 48 + n * 16 + l16) * 64 + ks * 32 + l4 * 8];
      }

#pragma unroll
    for (int m = 0; m < 4; ++m)
#pragma unroll
      for (int n = 0; n < 3; ++n) {
        acc[m][n] = __builtin_amdgcn_mfma_f32_16x16x32_bf16(af[0][m], bh[0][n], acc[m][n], 0, 0, 0);
        acc[m][n] = __builtin_amdgcn_mfma_f32_16x16x32_bf16(af[1][m], bh[1][n], acc[m][n], 0, 0, 0);
        acc[m][n] = __builtin_amdgcn_mfma_f32_16x16x32_bf16(af[0][m], bl[0][n], acc[m][n], 0, 0, 0);
        acc[m][n] = __builtin_amdgcn_mfma_f32_16x16x32_bf16(af[1][m], bl[1][n], acc[m][n], 0, 0, 0);
      }
    __syncthreads();
  }

  // epilogue: D row=(lane>>4)*4+reg, col=lane&15 (m89-verified); store fp16
#pragma unroll
  for (int m = 0; m < 4; ++m) {
    int grow = row0 + wr * 64 + m * 16 + l4 * 4;
#pragma unroll
    for (int n = 0; n < 3; ++n) {
      int gcol = col0 + wc * 48 + n * 16 + l16;
#pragma unroll
      for (int r = 0; r < 4; ++r)
        C[(size_t)(grow + r) * DD + gcol] = f2h(acc[m][n][r]);
    }
  }
}

// ---------- assembly: one block per token (XCD-swizzled), loops its 12 spans ----------
__global__ __launch_bounds__(192) void assemble_k(const int* __restrict__ span,
                                                  const unsigned short* __restrict__ U,
                                                  const unsigned short* __restrict__ V,
                                                  const unsigned short* __restrict__ us,
                                                  const unsigned short* __restrict__ vs,
                                                  const float* __restrict__ bias,
                                                  float* __restrict__ out) {
  const int bid = blockIdx.x;
  const int tk = (bid & 7) * (TT / 8) + (bid >> 3);   // XCD-chunked token order
  const int b = tk >> 9;                     // /512
  const int l = tk & 511;
  const int t0 = b * LLEN;
  const int e4 = threadIdx.x;                // 0..191, covers 4 e's
  const u16x4* U4 = (const u16x4*)U;
  const u16x4* V4 = (const u16x4*)V;
  const f32x4 bb = ((const f32x4*)bias)[e4];
  const int2* sp = (const int2*)(span + ((size_t)b * SS + (size_t)l * MW) * 2);
  f32x4* out4 = (f32x4*)out + ((size_t)b * SS + (size_t)l * MW) * 192 + e4;

#pragma unroll 4
  for (int wdx = 0; wdx < MW; ++wdx) {
    const int2 se = sp[wdx];
    const int start = se.x, end = se.y;
    u16x4 pe = U4[(size_t)(t0 + end) * 192 + e4];
    u16x4 pv = (end + 1 >= LLEN) ? ((const u16x4*)vs)[e4]
                                 : V4[(size_t)(t0 + end + 1) * 192 + e4];
    u16x4 mu = (start == 0) ? ((const u16x4*)us)[e4]
                            : U4[(size_t)(t0 + start - 1) * 192 + e4];
    u16x4 mv = V4[(size_t)(t0 + start) * 192 + e4];
    f32x4 r;
#pragma unroll
    for (int j = 0; j < 4; ++j) {
      float x = h2f(pe[j]) + h2f(pv[j]) - h2f(mu[j]) - h2f(mv[j]) + bb[j];
      r[j] = fmaxf(x, 0.f);
    }
    out4[(size_t)wdx * 192] = r;
  }
}

// ---------- naive fallback (only if ws too small) ----------
__global__ __launch_bounds__(256) void naive_k(const float* __restrict__ h,
                                               const int* __restrict__ span,
                                               const float* __restrict__ W,
                                               const float* __restrict__ bias,
                                               const float* __restrict__ ss,
                                               const float* __restrict__ es,
                                               float* __restrict__ out) {
  int bs = blockIdx.x;
  int b = bs / SS;
  int start = span[(size_t)bs * 2 + 0];
  int end   = span[(size_t)bs * 2 + 1];
  __shared__ float rep[DD];
  const float* hb = h + (size_t)b * LLEN * DD;
  for (int k = threadIdx.x; k < HH; k += blockDim.x) {
    float fs = (start == 0) ? ss[k] : hb[(size_t)(start - 1) * DD + k];
    rep[k] = hb[(size_t)end * DD + k] - fs;
    float bstart = (end + 1 >= LLEN) ? es[k] : hb[(size_t)(end + 1) * DD + HH + k];
    rep[HH + k] = bstart - hb[(size_t)start * DD + HH + k];
  }
  __syncthreads();
  for (int e = threadIdx.x; e < DD; e += blockDim.x) {
    const float* w = W + (size_t)e * DD;
    float acc = bias[e];
    for (int k = 0; k < DD; k += 4) {
      acc += rep[k] * w[k] + rep[k + 1] * w[k + 1] + rep[k + 2] * w[k + 2] + rep[k + 3] * w[k + 3];
    }
    out[(size_t)bs * DD + e] = fmaxf(acc, 0.f);
  }
}

extern "C" void kernel_launch(void* const* d_in, const int* in_sizes, int n_in,
                              void* d_out, int out_size, void* d_ws, size_t ws_size,
                              hipStream_t stream) {
  const float* h  = (const float*)d_in[0];
  const int* span = (const int*)d_in[1];
  const float* W  = (const float*)d_in[2];
  const float* bias = (const float*)d_in[3];
  const float* ss = (const float*)d_in[4];
  const float* es = (const float*)d_in[5];
  float* out = (float*)d_out;

  const size_t szUV = (size_t)MM * DD * sizeof(unsigned short);   // 12.58 MB (U+V fp16)
  const size_t szA  = (size_t)MM * HH * sizeof(unsigned short);   // 6.29 MB (hi only)
  const size_t szB  = (size_t)DD * HH * sizeof(unsigned short);   // 0.59 MB (each)
  const size_t szS  = DD * sizeof(unsigned short);
  const size_t need = szUV + szA + 4 * szB + 2 * szS;             // ~21.3 MB

  if (ws_size < need) {
    naive_k<<<NB * SS, 256, 0, stream>>>(h, span, W, bias, ss, es, out);
    return;
  }

  char* ws = (char*)d_ws;
  unsigned short* U    = (unsigned short*)ws;              // [TT][DD] fp16
  unsigned short* V    = U + (size_t)TT * DD;              // [TT][DD] fp16
  unsigned short* Ahi  = (unsigned short*)(ws + szUV);
  unsigned short* Buhi = Ahi + (size_t)MM * HH;
  unsigned short* Bulo = Buhi + (size_t)DD * HH;
  unsigned short* Bvhi = Bulo + (size_t)DD * HH;
  unsigned short* Bvlo = Bvhi + (size_t)DD * HH;
  unsigned short* us   = Bvlo + (size_t)DD * HH;
  unsigned short* vs   = us + DD;

  prep_k<<<PREP_BLOCKS, 256, 0, stream>>>(h, W, ss, es, Ahi, Buhi, Bulo, Bvhi, Bvlo, us, vs);
  gemm_k<<<512, 256, 0, stream>>>(Ahi, Buhi, Bulo, Bvhi, Bvlo, U);
  assemble_k<<<TT, 192, 0, stream>>>(span, U, V, us, vs, bias, out);
}

// Round 8
// 51.132 us; speedup vs baseline: 1.4915x; 1.0430x over previous
//
#include <hip/hip_runtime.h>

typedef __attribute__((ext_vector_type(4))) float f32x4;
typedef __attribute__((ext_vector_type(8))) _Float16 f16x8;
typedef __attribute__((ext_vector_type(4))) unsigned short u16x4;

#define NB 8
#define LLEN 512
#define DD 768
#define MW 12
#define HH 384
#define TT (NB * LLEN)      // 4096 tokens
#define SS (LLEN * MW)      // 6144 spans per batch
#define MM (2 * TT)         // 8192 fused GEMM rows (U rows then V rows)

#define PACKH_BLOCKS ((TT * 192) / 256)   // 3072
#define PACKW_BLOCKS ((DD * 192) / 256)   // 576
#define SENT_BLOCKS (DD / 4)              // 192
#define PREP_BLOCKS (PACKH_BLOCKS + PACKW_BLOCKS + SENT_BLOCKS)

// ---------- helpers ----------
__device__ __forceinline__ unsigned short f2h(float x) {
  _Float16 h = (_Float16)x;               // RNE
  return __builtin_bit_cast(unsigned short, h);
}
__device__ __forceinline__ float h2f(unsigned short u) {
  return (float)__builtin_bit_cast(_Float16, u);
}
__device__ __forceinline__ void gload_lds16(const void* g, void* l) {
  __builtin_amdgcn_global_load_lds(
      (const __attribute__((address_space(1))) unsigned int*)g,
      (__attribute__((address_space(3))) unsigned int*)l, 16, 0, 0);
}

// ---------- prep: h -> A [MM][HH] fp16 (fwd rows 0..TT-1, bwd rows TT..),
//                  W -> Bu, Bv [DD][HH] fp16; sentinels -> us,vs fp16 ----------
__global__ __launch_bounds__(256) void prep_k(const float* __restrict__ h,
                                              const float* __restrict__ W,
                                              const float* __restrict__ ss,
                                              const float* __restrict__ es,
                                              unsigned short* __restrict__ A,
                                              unsigned short* __restrict__ Bu,
                                              unsigned short* __restrict__ Bv,
                                              unsigned short* __restrict__ us,
                                              unsigned short* __restrict__ vs) {
  int bid = blockIdx.x;
  if (bid < PACKH_BLOCKS) {
    int idx = bid * 256 + threadIdx.x;        // over TT*192 float4s
    int t = idx / 192;
    int k = (idx - t * 192) * 4;
    f32x4 f = *(const f32x4*)(h + (size_t)idx * 4);
    int row = (k < HH) ? t : TT + t;          // fwd half -> U rows, bwd -> V rows
    int kk = (k < HH) ? k : k - HH;
    u16x4 v;
#pragma unroll
    for (int j = 0; j < 4; ++j) v[j] = f2h(f[j]);
    *(u16x4*)(A + (size_t)row * HH + kk) = v;
  } else if (bid < PACKH_BLOCKS + PACKW_BLOCKS) {
    int idx = (bid - PACKH_BLOCKS) * 256 + threadIdx.x;  // over DD*192 float4s
    int e = idx / 192;
    int k = (idx - e * 192) * 4;
    f32x4 f = *(const f32x4*)(W + (size_t)idx * 4);
    unsigned short* Bm = (k < HH) ? Bu : Bv;
    int kk = (k < HH) ? k : k - HH;
    u16x4 v;
#pragma unroll
    for (int j = 0; j < 4; ++j) v[j] = f2h(f[j]);
    *(u16x4*)(Bm + (size_t)e * HH + kk) = v;
  } else {
    // sentinel projections: 4 e-values per block, 64 lanes each (f32 math)
    int e = (bid - PACKH_BLOCKS - PACKW_BLOCKS) * 4 + (threadIdx.x >> 6);
    int lane = threadIdx.x & 63;
    float a = 0.f, b = 0.f;
    const float* w = W + (size_t)e * DD;
    for (int j = lane; j < HH; j += 64) {
      a += ss[j] * w[j];
      b += es[j] * w[HH + j];
    }
#pragma unroll
    for (int off = 32; off > 0; off >>= 1) {
      a += __shfl_down(a, off);
      b += __shfl_down(b, off);
    }
    if (lane == 0) { us[e] = f2h(a); vs[e] = f2h(b); }
  }
}

// ---------- fp16 GEMM: C[8192][768] = A[M][HH] * B^T[N][HH], C fp16 ----------
// Single pass (fp16 operands: rel err 2^-11 < bf16's 2^-9 — better AND 2x fewer FLOPs).
// BM=128, BN=96, 6 kc-iters; 28 KB LDS. Grid 512 = 2/CU; bid&63 keeps an
// M-panel's 8 N-blocks on one XCD (L2-resident A).
__global__ __launch_bounds__(256) void gemm_k(const unsigned short* __restrict__ A,
                                              const unsigned short* __restrict__ Bu,
                                              const unsigned short* __restrict__ Bv,
                                              unsigned short* __restrict__ C) {
  __shared__ unsigned short As[128 * 64];    // 16 KB
  __shared__ unsigned short Bs[96 * 64];     // 12 KB

  const int bid = blockIdx.x;
  const int bx = bid & 63, by = bid >> 6;
  const int tid = threadIdx.x;
  const int lane = tid & 63;
  const int w = tid >> 6;
  const int wr = w >> 1, wc = w & 1;         // 2x2 waves -> each 64x48
  const int l16 = lane & 15, l4 = lane >> 4;
  const int row0 = bx * 128;
  const int col0 = by * 96;
  const char* Bb = (const char*)((row0 < TT) ? Bu : Bv);
  const char* Ab = (const char*)A;

  f32x4 acc[4][3] = {};

  for (int kc = 0; kc < HH; kc += 64) {
    // stage A 128x64 (4 loads/thread), B 96x64 (3 loads/thread)
#pragma unroll
    for (int r = 0; r < 4; ++r) {
      int o = (r * 256 + tid) * 16;          // byte offset; 128 B per LDS row
      int row = o >> 7, colb = o & 127;
      gload_lds16(Ab + ((size_t)(row0 + row) * HH + kc) * 2 + colb, (char*)As + o);
    }
#pragma unroll
    for (int r = 0; r < 3; ++r) {
      int o = (r * 256 + tid) * 16;
      int row = o >> 7, colb = o & 127;
      gload_lds16(Bb + ((size_t)(col0 + row) * HH + kc) * 2 + colb, (char*)Bs + o);
    }
    __syncthreads();

    f16x8 af[2][4], bf[2][3];
#pragma unroll
    for (int ks = 0; ks < 2; ++ks)
#pragma unroll
      for (int m = 0; m < 4; ++m)
        af[ks][m] = *(const f16x8*)&As[(wr * 64 + m * 16 + l16) * 64 + ks * 32 + l4 * 8];
#pragma unroll
    for (int ks = 0; ks < 2; ++ks)
#pragma unroll
      for (int n = 0; n < 3; ++n)
        bf[ks][n] = *(const f16x8*)&Bs[(wc * 48 + n * 16 + l16) * 64 + ks * 32 + l4 * 8];

#pragma unroll
    for (int m = 0; m < 4; ++m)
#pragma unroll
      for (int n = 0; n < 3; ++n) {
        acc[m][n] = __builtin_amdgcn_mfma_f32_16x16x32_f16(af[0][m], bf[0][n], acc[m][n], 0, 0, 0);
        acc[m][n] = __builtin_amdgcn_mfma_f32_16x16x32_f16(af[1][m], bf[1][n], acc[m][n], 0, 0, 0);
      }
    __syncthreads();
  }

  // epilogue: D row=(lane>>4)*4+reg, col=lane&15 (m89-verified; dtype-independent); store fp16
#pragma unroll
  for (int m = 0; m < 4; ++m) {
    int grow = row0 + wr * 64 + m * 16 + l4 * 4;
#pragma unroll
    for (int n = 0; n < 3; ++n) {
      int gcol = col0 + wc * 48 + n * 16 + l16;
#pragma unroll
      for (int r = 0; r < 4; ++r)
        C[(size_t)(grow + r) * DD + gcol] = f2h(acc[m][n][r]);
    }
  }
}

// ---------- assembly: one block per token (XCD-swizzled), loops its 12 spans ----------
__global__ __launch_bounds__(192) void assemble_k(const int* __restrict__ span,
                                                  const unsigned short* __restrict__ U,
                                                  const unsigned short* __restrict__ V,
                                                  const unsigned short* __restrict__ us,
                                                  const unsigned short* __restrict__ vs,
                                                  const float* __restrict__ bias,
                                                  float* __restrict__ out) {
  const int bid = blockIdx.x;
  const int tk = (bid & 7) * (TT / 8) + (bid >> 3);   // XCD-chunked token order
  const int b = tk >> 9;                     // /512
  const int l = tk & 511;
  const int t0 = b * LLEN;
  const int e4 = threadIdx.x;                // 0..191, covers 4 e's
  const u16x4* U4 = (const u16x4*)U;
  const u16x4* V4 = (const u16x4*)V;
  const f32x4 bb = ((const f32x4*)bias)[e4];
  const int2* sp = (const int2*)(span + ((size_t)b * SS + (size_t)l * MW) * 2);
  f32x4* out4 = (f32x4*)out + ((size_t)b * SS + (size_t)l * MW) * 192 + e4;

#pragma unroll 4
  for (int wdx = 0; wdx < MW; ++wdx) {
    const int2 se = sp[wdx];
    const int start = se.x, end = se.y;
    u16x4 pe = U4[(size_t)(t0 + end) * 192 + e4];
    u16x4 pv = (end + 1 >= LLEN) ? ((const u16x4*)vs)[e4]
                                 : V4[(size_t)(t0 + end + 1) * 192 + e4];
    u16x4 mu = (start == 0) ? ((const u16x4*)us)[e4]
                            : U4[(size_t)(t0 + start - 1) * 192 + e4];
    u16x4 mv = V4[(size_t)(t0 + start) * 192 + e4];
    f32x4 r;
#pragma unroll
    for (int j = 0; j < 4; ++j) {
      float x = h2f(pe[j]) + h2f(pv[j]) - h2f(mu[j]) - h2f(mv[j]) + bb[j];
      r[j] = fmaxf(x, 0.f);
    }
    out4[(size_t)wdx * 192] = r;
  }
}

// ---------- naive fallback (only if ws too small) ----------
__global__ __launch_bounds__(256) void naive_k(const float* __restrict__ h,
                                               const int* __restrict__ span,
                                               const float* __restrict__ W,
                                               const float* __restrict__ bias,
                                               const float* __restrict__ ss,
                                               const float* __restrict__ es,
                                               float* __restrict__ out) {
  int bs = blockIdx.x;
  int b = bs / SS;
  int start = span[(size_t)bs * 2 + 0];
  int end   = span[(size_t)bs * 2 + 1];
  __shared__ float rep[DD];
  const float* hb = h + (size_t)b * LLEN * DD;
  for (int k = threadIdx.x; k < HH; k += blockDim.x) {
    float fs = (start == 0) ? ss[k] : hb[(size_t)(start - 1) * DD + k];
    rep[k] = hb[(size_t)end * DD + k] - fs;
    float bstart = (end + 1 >= LLEN) ? es[k] : hb[(size_t)(end + 1) * DD + HH + k];
    rep[HH + k] = bstart - hb[(size_t)start * DD + HH + k];
  }
  __syncthreads();
  for (int e = threadIdx.x; e < DD; e += blockDim.x) {
    const float* w = W + (size_t)e * DD;
    float acc = bias[e];
    for (int k = 0; k < DD; k += 4) {
      acc += rep[k] * w[k] + rep[k + 1] * w[k + 1] + rep[k + 2] * w[k + 2] + rep[k + 3] * w[k + 3];
    }
    out[(size_t)bs * DD + e] = fmaxf(acc, 0.f);
  }
}

extern "C" void kernel_launch(void* const* d_in, const int* in_sizes, int n_in,
                              void* d_out, int out_size, void* d_ws, size_t ws_size,
                              hipStream_t stream) {
  const float* h  = (const float*)d_in[0];
  const int* span = (const int*)d_in[1];
  const float* W  = (const float*)d_in[2];
  const float* bias = (const float*)d_in[3];
  const float* ss = (const float*)d_in[4];
  const float* es = (const float*)d_in[5];
  float* out = (float*)d_out;

  const size_t szUV = (size_t)MM * DD * sizeof(unsigned short);   // 12.58 MB (U+V fp16)
  const size_t szA  = (size_t)MM * HH * sizeof(unsigned short);   // 6.29 MB
  const size_t szB  = (size_t)DD * HH * sizeof(unsigned short);   // 0.59 MB (each of u,v)
  const size_t szS  = DD * sizeof(unsigned short);
  const size_t need = szUV + szA + 2 * szB + 2 * szS;             // ~20.1 MB

  if (ws_size < need) {
    naive_k<<<NB * SS, 256, 0, stream>>>(h, span, W, bias, ss, es, out);
    return;
  }

  char* ws = (char*)d_ws;
  unsigned short* U  = (unsigned short*)ws;                // [TT][DD] fp16
  unsigned short* V  = U + (size_t)TT * DD;                // [TT][DD] fp16
  unsigned short* A  = (unsigned short*)(ws + szUV);       // [MM][HH] fp16
  unsigned short* Bu = A + (size_t)MM * HH;
  unsigned short* Bv = Bu + (size_t)DD * HH;
  unsigned short* us = Bv + (size_t)DD * HH;
  unsigned short* vs = us + DD;

  prep_k<<<PREP_BLOCKS, 256, 0, stream>>>(h, W, ss, es, A, Bu, Bv, us, vs);
  gemm_k<<<512, 256, 0, stream>>>(A, Bu, Bv, U);
  assemble_k<<<TT, 192, 0, stream>>>(span, U, V, us, vs, bias, out);
}